// Round 7
// baseline (9291.969 us; speedup 1.0000x reference)
//
#include <hip/hip_runtime.h>
#include <hip/hip_cooperative_groups.h>
#include <math.h>

namespace cg = cooperative_groups;

#define TPB 1024
#define NBLK 256
#define NBATCH 32
#define NT 64
#define NH 512
#define NM 128
#define NR 4
#define NW 64
#define NI 768          // controller input size (H + R*W)
#define NXI 471         // interface vector size
#define NG 2048         // gate rows
#define EPSF 1e-6f
#define MS 65           // mem row stride (+1 pad)

// ws layout (float offsets)
#define WS_LINK  0                                   // 32 x 2 x 128x128
#define WS_GATES (WS_LINK + NBATCH*2*NM*NM)          // 32 x 2 x 2048 (parity dbuf)
#define WS_CNT   (WS_GATES + (size_t)NBATCH*2*NG)    // 32 uint counters

__device__ __forceinline__ float sigm(float x){ return 1.0f/(1.0f+expf(-x)); }
__device__ __forceinline__ float sftp(float x){ return fmaxf(x,0.0f)+log1pf(expf(-fabsf(x))); }
__device__ __forceinline__ float dot4(float4 a, float4 b){
    return a.x*b.x + a.y*b.y + a.z*b.z + a.w*b.w;
}
__device__ __forceinline__ float wave_red(float v){
    #pragma unroll
    for (int o = 32; o > 0; o >>= 1) v += __shfl_down(v, o);
    return v;
}
// cross-XCD coherent accessors: RELAXED agent atomics bypass L2 (serve at
// the coherence point) WITHOUT emitting buffer_inv/wbl2 — L2 stays warm.
__device__ __forceinline__ void cstore(float* p, float v){
    __hip_atomic_store(p, v, __ATOMIC_RELAXED, __HIP_MEMORY_SCOPE_AGENT);
}
__device__ __forceinline__ float cload(const float* p){
    return __hip_atomic_load(p, __ATOMIC_RELAXED, __HIP_MEMORY_SCOPE_AGENT);
}

__global__ __launch_bounds__(TPB) void dnc_nollc(
    const float* __restrict__ x, const float* __restrict__ W_ih,
    const float* __restrict__ W_hh, const float* __restrict__ b_ih,
    const float* __restrict__ b_hh, const float* __restrict__ W_xi,
    const float* __restrict__ b_xi, const float* __restrict__ W_o,
    const float* __restrict__ b_o, float* __restrict__ out,
    float* __restrict__ ws)
{
    cg::grid_group grid = cg::this_grid();

    // -------- per-block private replicated state --------
    __shared__ float mem[NM*MS];
    __shared__ __align__(16) float hS[NH];
    __shared__ float cS[NH];
    __shared__ float rwS[NR*NM];
    __shared__ float wwO[NM], wwN[NM];
    __shared__ float usg[NM], prc[NM];
    __shared__ __align__(16) float inp[NI];      // [x_t | last_read]
    __shared__ float xiS[NXI+1];
    __shared__ float keys[NR*NW];
    __shared__ float wkey[NW], ers[NW], wvec[NW];
    __shared__ float rstr[NR], fgte[NR], modes[NR*3], nkey[NR];
    __shared__ float sc[8];               // 0:wstr 1:ag 2:wg 3:|wkey| 4:sum(ww)
    __shared__ float nmo[NM], nmn[NM];
    __shared__ float wcw[NM], uu[NM], su[NM], cum[NM];
    __shared__ int   rnk[NM];
    __shared__ float ccw[NR*NM];
    __shared__ float fwdT[NR*NM];
    __shared__ __align__(16) float rv[NR*NW];
    __shared__ float red[8];

    const int tid = threadIdx.x;
    const int wv  = tid >> 6;             // wave id 0..15
    const int l   = tid & 63;             // lane
    const int b   = blockIdx.x >> 3;      // batch
    const int s   = blockIdx.x & 7;       // slice (RR dispatch -> XCD affinity)

    float* __restrict__ lkBase = ws + WS_LINK + (size_t)b*2*NM*NM;
    unsigned int* __restrict__ cnt = (unsigned int*)(ws + WS_CNT);

    // -------- init --------
    for (int e = tid; e < 2*NM*NM; e += TPB) lkBase[e] = 0.0f;
    for (int e = tid; e < NM*NW; e += TPB) mem[(e>>6)*MS + (e&63)] = EPSF;
    for (int e = tid; e < NH; e += TPB){ hS[e]=0.0f; cS[e]=0.0f; }
    for (int e = tid; e < NR*NM; e += TPB) rwS[e]=0.0f;
    for (int e = tid; e < NM; e += TPB){ wwO[e]=0.0f; usg[e]=0.0f; prc[e]=0.0f; }
    for (int e = tid; e < NR*NW; e += TPB) inp[NH+e]=0.0f;
    if (s == 0 && tid == 0) cnt[b] = 0u;
    __syncthreads();
    grid.sync();   // one-time: counters + link-zero visible device-wide

    for (int t = 0; t < NT; ++t) {
        float* __restrict__ lkO = lkBase + (t & 1)*NM*NM;       // read (old)
        float* __restrict__ lkN = lkBase + ((t+1) & 1)*NM*NM;   // write (new)
        float* __restrict__ gatesBuf = ws + WS_GATES + ((size_t)b*2 + (t & 1))*NG;

        // ================= P1: x_t load + gates GEMV slice =================
        if (tid < NH) inp[tid] = x[((size_t)b*NT + t)*NH + tid];
        __syncthreads();
        {
            const float4* inp4 = (const float4*)inp;
            const float4* h4   = (const float4*)hS;
            float4 i0 = inp4[l], i1 = inp4[l+64], i2 = inp4[l+128];
            float4 hv0 = h4[l], hv1 = h4[l+64];
            const int rbase = s*256 + wv*16;
            for (int i = 0; i < 16; i += 2) {
                const int r0 = rbase + i, r1 = r0 + 1;
                const float4* A0 = (const float4*)(W_ih + (size_t)r0*NI);
                const float4* B0 = (const float4*)(W_hh + (size_t)r0*NH);
                const float4* A1 = (const float4*)(W_ih + (size_t)r1*NI);
                const float4* B1 = (const float4*)(W_hh + (size_t)r1*NH);
                float4 a00=A0[l], a01=A0[l+64], a02=A0[l+128];
                float4 b00=B0[l], b01=B0[l+64];
                float4 a10=A1[l], a11=A1[l+64], a12=A1[l+128];
                float4 b10=B1[l], b11=B1[l+64];
                float v0 = dot4(a00,i0)+dot4(a01,i1)+dot4(a02,i2)
                         + dot4(b00,hv0)+dot4(b01,hv1);
                float v1 = dot4(a10,i0)+dot4(a11,i1)+dot4(a12,i2)
                         + dot4(b10,hv0)+dot4(b11,hv1);
                v0 = wave_red(v0); v1 = wave_red(v1);
                if (l == 0) {
                    cstore(&gatesBuf[r0], v0 + b_ih[r0] + b_hh[r0]);
                    cstore(&gatesBuf[r1], v1 + b_ih[r1] + b_hh[r1]);
                }
            }
        }
        __syncthreads();   // every wave's sc1 stores vmcnt-drained (at LLC)

        // ===== S1: 8-block flag sync — NO acquire, NO L2 invalidate ========
        if (tid == 0) {
            __hip_atomic_fetch_add(&cnt[b], 1u, __ATOMIC_RELEASE,
                                   __HIP_MEMORY_SCOPE_AGENT);
            const unsigned int target = 8u*(unsigned)(t+1);
            while (__hip_atomic_load(&cnt[b], __ATOMIC_RELAXED,
                                     __HIP_MEMORY_SCOPE_AGENT) < target)
                __builtin_amdgcn_s_sleep(2);
        }
        __syncthreads();

        // ================= P2: LSTM pointwise (gates via LLC loads) ========
        if (tid < NH) {
            float ig = sigm(cload(&gatesBuf[tid]));
            float fg = sigm(cload(&gatesBuf[NH + tid]));
            float gg = tanhf(cload(&gatesBuf[2*NH + tid]));
            float og = sigm(cload(&gatesBuf[3*NH + tid]));
            float c = fg*cS[tid] + ig*gg;
            cS[tid] = c;
            hS[tid] = og*tanhf(c);
        }
        __syncthreads();

        // ================= P2b: xi GEMV (full, replicated) =================
        {
            const float4* h4 = (const float4*)hS;
            float4 hv0 = h4[l], hv1 = h4[l+64];
            for (int row = wv; row < NXI; row += 16) {
                const float4* Wc = (const float4*)(W_xi + (size_t)row*NH);
                float v = dot4(Wc[l], hv0) + dot4(Wc[l+64], hv1);
                v = wave_red(v);
                if (l == 0) xiS[row] = v + b_xi[row];
            }
        }
        __syncthreads();

        // ================= P3: replicated DNC machinery ====================
        // E1: unpack interface
        if (tid < 256)       keys[tid] = tanhf(xiS[tid]);
        else if (tid < 260)  rstr[tid-256] = sftp(xiS[tid]);
        else if (tid < 324)  wkey[tid-260] = tanhf(xiS[tid]);
        else if (tid == 324) sc[0] = sftp(xiS[324]);
        else if (tid < 389)  ers[tid-325] = sigm(xiS[tid]);
        else if (tid < 453)  wvec[tid-389] = tanhf(xiS[tid]);
        else if (tid < 457)  fgte[tid-453] = sigm(xiS[tid]);
        else if (tid == 457) sc[1] = sigm(xiS[457]);
        else if (tid == 458) sc[2] = sigm(xiS[458]);
        else if (tid < 463) {
            int r = tid - 459;
            float a0=xiS[459+3*r], a1=xiS[460+3*r], a2=xiS[461+3*r];
            float mx = fmaxf(a0, fmaxf(a1, a2));
            float e0=expf(a0-mx), e1=expf(a1-mx), e2=expf(a2-mx);
            float si = 1.0f/(e0+e1+e2);
            modes[3*r]=e0*si; modes[3*r+1]=e1*si; modes[3*r+2]=e2*si;
        }
        __syncthreads();

        // E2a: old mem norms + key norms
        if (tid < NM) {
            float ssum = 0.0f;
            for (int w = 0; w < NW; ++w) { float v = mem[tid*MS+w]; ssum += v*v; }
            nmo[tid] = sqrtf(ssum);
        } else if (tid < NM+NR) {
            int r = tid - NM; float ssum = 0.0f;
            for (int w = 0; w < NW; ++w) { float v = keys[r*NW+w]; ssum += v*v; }
            nkey[r] = sqrtf(ssum);
        } else if (tid == NM+NR) {
            float ssum = 0.0f;
            for (int w = 0; w < NW; ++w) { float v = wkey[w]; ssum += v*v; }
            sc[3] = sqrtf(ssum);
        }
        __syncthreads();

        // E2b: usage update
        if (tid < NM) {
            float u = usg[tid];
            u = u + (1.0f - u)*wwO[tid];
            float psi = 1.0f;
            #pragma unroll
            for (int r = 0; r < NR; ++r) psi *= (1.0f - fgte[r]*rwS[r*NM+tid]);
            usg[tid] = u*psi;
        }
        __syncthreads();

        // F1: write-content logits
        if (tid < NM) {
            float d = 0.0f;
            for (int w = 0; w < NW; ++w) d += wkey[w]*mem[tid*MS+w];
            wcw[tid] = d/(sc[3]*nmo[tid] + EPSF) * sc[0];
        }
        __syncthreads();
        // F2: softmax over 128
        if (tid < 64) {
            float v = fmaxf(wcw[tid], wcw[tid+64]);
            #pragma unroll
            for (int o = 32; o > 0; o >>= 1) v = fmaxf(v, __shfl_down(v, o));
            if (tid == 0) red[0] = v;
        }
        __syncthreads();
        if (tid < NM) wcw[tid] = expf(wcw[tid] - red[0]);
        __syncthreads();
        if (tid < 64) {
            float v = wave_red(wcw[tid] + wcw[tid+64]);
            if (tid == 0) red[0] = 1.0f/v;
        }
        __syncthreads();
        if (tid < NM) wcw[tid] *= red[0];
        __syncthreads();

        // G1: u
        if (tid < NM) uu[tid] = 5e-6f + (1.0f - 5e-6f)*usg[tid];
        __syncthreads();
        // G2: stable rank
        if (tid < NM) {
            float um = uu[tid]; int rk = 0;
            for (int j = 0; j < NM; ++j) {
                float uj = uu[j];
                rk += (uj < um) || (uj == um && j < tid);
            }
            rnk[tid] = rk;
            su[rk] = um;
        }
        __syncthreads();
        // G3: product scan via wave-0 shfl
        if (tid < 64) {
            float a = su[tid], bb = su[64+tid];
            #pragma unroll
            for (int o = 1; o < 64; o <<= 1) {
                float ta = __shfl_up(a, o);
                float tb = __shfl_up(bb, o);
                if (tid >= o) { a *= ta; bb *= tb; }
            }
            float P0 = __shfl(a, 63);
            cum[tid] = a;
            cum[64+tid] = P0*bb;
        }
        __syncthreads();
        // G4: alloc + write weighting
        if (tid < NM) {
            int rk = rnk[tid];
            float excl = (rk == 0) ? 1.0f : cum[rk-1];
            float al = (1.0f - uu[tid])*excl;
            wwN[tid] = sc[2]*(sc[1]*al + (1.0f - sc[1])*wcw[tid]);
        }
        __syncthreads();
        // G5: sum(wwN)
        if (tid < 64) {
            float v = wave_red(wwN[tid] + wwN[tid+64]);
            if (tid == 0) sc[4] = v;
        }
        __syncthreads();

        // H1: erase+write mem; link update lkO -> lkN
        for (int e = tid; e < NM*NW; e += TPB) {
            int m = e >> 6, w = e & 63;
            float wm = wwN[m];
            mem[m*MS+w] = mem[m*MS+w]*(1.0f - wm*ers[w]) + wm*wvec[w];
        }
        for (int e = tid; e < NM*NM; e += TPB) {
            int i = e >> 7, j = e & 127;
            float nl = (i == j) ? 0.0f
                     : (1.0f - wwN[i] - wwN[j])*lkO[e] + wwN[i]*prc[j];
            lkN[e] = nl;
        }
        __syncthreads();
        // H2: new mem norms
        if (tid < NM) {
            float ssum = 0.0f;
            for (int w = 0; w < NW; ++w) { float v = mem[tid*MS+w]; ssum += v*v; }
            nmn[tid] = sqrtf(ssum);
        }
        __syncthreads();
        // H3: precedence
        if (tid < NM) prc[tid] = (1.0f - sc[4])*prc[tid] + wwN[tid];
        __syncthreads();

        // I: read-content logits + per-r softmax
        if (tid < NR*NM) {
            int r = tid >> 7, m = tid & 127;
            float d = 0.0f;
            for (int w = 0; w < NW; ++w) d += keys[r*NW+w]*mem[m*MS+w];
            ccw[tid] = d/(nkey[r]*nmn[m] + EPSF) * rstr[r];
        }
        __syncthreads();
        if (tid < 256) {
            int r = tid >> 6, ll = tid & 63;
            float v = fmaxf(ccw[r*NM+ll], ccw[r*NM+ll+64]);
            #pragma unroll
            for (int o = 32; o > 0; o >>= 1) v = fmaxf(v, __shfl_down(v, o));
            if (ll == 0) red[r] = v;
        }
        __syncthreads();
        if (tid < NR*NM) ccw[tid] = expf(ccw[tid] - red[tid>>7]);
        __syncthreads();
        if (tid < 256) {
            int r = tid >> 6, ll = tid & 63;
            float v = wave_red(ccw[r*NM+ll] + ccw[r*NM+ll+64]);
            if (ll == 0) red[4+r] = 1.0f/v;
        }
        __syncthreads();
        if (tid < NR*NM) ccw[tid] *= red[4+(tid>>7)];
        __syncthreads();

        // J1: fwd — wave-parallel over j (coalesced)
        {
            const int p0 = wv*32;
            for (int i = 0; i < 32; ++i) {
                const int p = p0 + i, r = p >> 7, m = p & 127;
                float partial = lkN[m*NM + l]*rwS[r*NM + l]
                              + lkN[m*NM + 64 + l]*rwS[r*NM + 64 + l];
                partial = wave_red(partial);
                if (l == 0) fwdT[p] = partial;
            }
        }
        __syncthreads();
        // J2: bwd (coalesced over m) + mode mix
        float rwnew = 0.0f;
        if (tid < NR*NM) {
            int r = tid >> 7, m = tid & 127;
            float bw = 0.0f;
            for (int i = 0; i < NM; ++i) bw += lkN[i*NM+m]*rwS[r*NM+i];
            rwnew = modes[3*r]*bw + modes[3*r+1]*fwdT[tid] + modes[3*r+2]*ccw[tid];
        }
        __syncthreads();
        if (tid < NR*NM) rwS[tid] = rwnew;
        __syncthreads();

        // K: read vectors
        if (tid < NR*NW) {
            int r = tid >> 6, w = tid & 63;
            float ssum = 0.0f;
            for (int m = 0; m < NM; ++m) ssum += rwS[r*NM+m]*mem[m*MS+w];
            rv[tid] = ssum;
        }
        __syncthreads();

        // ================= out GEMV slice (64 rows/block) ==================
        {
            const float4* h4  = (const float4*)hS;
            const float4* rv4 = (const float4*)rv;
            float4 hv0 = h4[l], hv1 = h4[l+64], rvv = rv4[l];
            const int rbase = s*64 + wv*4;
            for (int i = 0; i < 4; ++i) {
                const int row = rbase + i;
                const float4* Wo = (const float4*)(W_o + (size_t)row*NI);
                float v = dot4(Wo[l],hv0) + dot4(Wo[l+64],hv1) + dot4(Wo[l+128],rvv);
                v = wave_red(v);
                if (l == 0) out[((size_t)b*NT + t)*NH + row] = v + b_o[row];
            }
        }
        __syncthreads();

        // M: carries
        if (tid < NR*NW) inp[NH + tid] = rv[tid];
        else if (tid < NR*NW + NM) wwO[tid - NR*NW] = wwN[tid - NR*NW];
        __syncthreads();
    }
}

extern "C" void kernel_launch(void* const* d_in, const int* in_sizes, int n_in,
                              void* d_out, int out_size, void* d_ws, size_t ws_size,
                              hipStream_t stream) {
    (void)in_sizes; (void)n_in; (void)out_size; (void)ws_size;
    const float* x    = (const float*)d_in[0];
    const float* W_ih = (const float*)d_in[1];
    const float* W_hh = (const float*)d_in[2];
    const float* b_ih = (const float*)d_in[3];
    const float* b_hh = (const float*)d_in[4];
    const float* W_xi = (const float*)d_in[5];
    const float* b_xi = (const float*)d_in[6];
    const float* W_o  = (const float*)d_in[7];
    const float* b_o  = (const float*)d_in[8];
    float* out = (float*)d_out;
    float* ws  = (float*)d_ws;

    void* args[] = { (void*)&x, (void*)&W_ih, (void*)&W_hh, (void*)&b_ih,
                     (void*)&b_hh, (void*)&W_xi, (void*)&b_xi, (void*)&W_o,
                     (void*)&b_o, (void*)&out, (void*)&ws };
    hipLaunchCooperativeKernel((void*)dnc_nollc, dim3(NBLK), dim3(TPB),
                               args, 0, stream);
}

// Round 8
// 7416.587 us; speedup vs baseline: 1.2529x; 1.2529x over previous
//
#include <hip/hip_runtime.h>
#include <hip/hip_cooperative_groups.h>
#include <math.h>

namespace cg = cooperative_groups;

#define TPB 1024
#define NBLK 256
#define NBATCH 32
#define NT 64
#define NH 512
#define NM 128
#define NR 4
#define NW 64
#define NI 768          // controller input size (H + R*W)
#define NXI 471         // interface vector size
#define NG 2048         // gate rows
#define SL 16           // link rows per slice (128/8)
#define EPSF 1e-6f
#define MS 65           // mem row stride (+1 pad)

// ws layout (float offsets)
#define WS_LINK  0                                    // [32][8][16*128] private slices
#define WS_GATES (WS_LINK + NBATCH*8*SL*NM)           // [32][2][2048] parity dbuf
#define WS_FWD   (WS_GATES + NBATCH*2*NG)             // [32][512]
#define WS_BWDP  (WS_FWD + NBATCH*NR*NM)              // [32][8][512]
#define WS_CNTA  (WS_BWDP + NBATCH*8*NR*NM)           // 32 uints
#define WS_CNTB  (WS_CNTA + NBATCH)                   // 32 uints

__device__ __forceinline__ float sigm(float x){ return 1.0f/(1.0f+expf(-x)); }
__device__ __forceinline__ float sftp(float x){ return fmaxf(x,0.0f)+log1pf(expf(-fabsf(x))); }
__device__ __forceinline__ float dot4(float4 a, float4 b){
    return a.x*b.x + a.y*b.y + a.z*b.z + a.w*b.w;
}
__device__ __forceinline__ float wave_red(float v){
    #pragma unroll
    for (int o = 32; o > 0; o >>= 1) v += __shfl_down(v, o);
    return v;
}
// cross-XCD coherent accessors (LLC, bypass L2, no invalidates)
__device__ __forceinline__ void cstore(float* p, float v){
    __hip_atomic_store(p, v, __ATOMIC_RELAXED, __HIP_MEMORY_SCOPE_AGENT);
}
__device__ __forceinline__ float cload(const float* p){
    return __hip_atomic_load(p, __ATOMIC_RELAXED, __HIP_MEMORY_SCOPE_AGENT);
}
__device__ __forceinline__ void flag_sync(unsigned int* c, unsigned int target,
                                          int tid){
    if (tid == 0) {
        __hip_atomic_fetch_add(c, 1u, __ATOMIC_RELEASE, __HIP_MEMORY_SCOPE_AGENT);
        while (__hip_atomic_load(c, __ATOMIC_RELAXED,
                                 __HIP_MEMORY_SCOPE_AGENT) < target)
            __builtin_amdgcn_s_sleep(2);
    }
    __syncthreads();
}

__global__ __launch_bounds__(TPB) void dnc_sliced(
    const float* __restrict__ x, const float* __restrict__ W_ih,
    const float* __restrict__ W_hh, const float* __restrict__ b_ih,
    const float* __restrict__ b_hh, const float* __restrict__ W_xi,
    const float* __restrict__ b_xi, const float* __restrict__ W_o,
    const float* __restrict__ b_o, float* __restrict__ out,
    float* __restrict__ ws)
{
    cg::grid_group grid = cg::this_grid();

    // -------- per-block private replicated state --------
    __shared__ float mem[NM*MS];
    __shared__ __align__(16) float hS[NH];
    __shared__ float cS[NH];
    __shared__ float rwS[NR*NM];
    __shared__ float wwO[NM], wwN[NM];
    __shared__ float usg[NM], prc[NM];
    __shared__ __align__(16) float inp[NI];      // [x_t | last_read]
    __shared__ float xiS[NXI+1];
    __shared__ float keys[NR*NW];
    __shared__ float wkey[NW], ers[NW], wvec[NW];
    __shared__ float rstr[NR], fgte[NR], modes[NR*3], nkey[NR];
    __shared__ float sc[8];               // 0:wstr 1:ag 2:wg 3:|wkey| 4:sum(ww)
    __shared__ float nmo[NM], nmn[NM];
    __shared__ float wcw[NM], uu[NM], su[NM], cum[NM];
    __shared__ int   rnk[NM];
    __shared__ float ccw[NR*NM];
    __shared__ __align__(16) float rv[NR*NW];
    __shared__ float red[8];

    const int tid = threadIdx.x;
    const int wv  = tid >> 6;             // wave id 0..15
    const int l   = tid & 63;             // lane
    const int b   = blockIdx.x >> 3;      // batch
    const int s   = blockIdx.x & 7;       // slice (RR dispatch -> XCD affinity)

    float* __restrict__ lkS     = ws + WS_LINK + ((size_t)b*8 + s)*SL*NM; // PRIVATE
    float* __restrict__ fwdBuf  = ws + WS_FWD  + (size_t)b*NR*NM;
    float* __restrict__ bwdBuf  = ws + WS_BWDP + ((size_t)b*8 + s)*NR*NM;
    float* __restrict__ bwdBufB = ws + WS_BWDP + (size_t)b*8*NR*NM;
    unsigned int* __restrict__ cntA = (unsigned int*)(ws + WS_CNTA);
    unsigned int* __restrict__ cntB = (unsigned int*)(ws + WS_CNTB);

    // -------- init --------
    for (int e = tid; e < SL*NM; e += TPB) lkS[e] = 0.0f;   // own slice only
    for (int e = tid; e < NM*NW; e += TPB) mem[(e>>6)*MS + (e&63)] = EPSF;
    for (int e = tid; e < NH; e += TPB){ hS[e]=0.0f; cS[e]=0.0f; }
    for (int e = tid; e < NR*NM; e += TPB) rwS[e]=0.0f;
    for (int e = tid; e < NM; e += TPB){ wwO[e]=0.0f; usg[e]=0.0f; prc[e]=0.0f; }
    for (int e = tid; e < NR*NW; e += TPB) inp[NH+e]=0.0f;
    if (s == 0 && tid == 0) { cntA[b] = 0u; cntB[b] = 0u; }
    __syncthreads();
    grid.sync();   // one-time: counters + link zero visible

    for (int t = 0; t < NT; ++t) {
        float* __restrict__ gatesBuf = ws + WS_GATES + ((size_t)b*2 + (t & 1))*NG;

        // ================= P1: x_t load + gates GEMV slice =================
        if (tid < NH) inp[tid] = x[((size_t)b*NT + t)*NH + tid];
        __syncthreads();
        {
            const float4* inp4 = (const float4*)inp;
            const float4* h4   = (const float4*)hS;
            float4 i0 = inp4[l], i1 = inp4[l+64], i2 = inp4[l+128];
            float4 hv0 = h4[l], hv1 = h4[l+64];
            const int rbase = s*256 + wv*16;
            for (int i = 0; i < 16; i += 2) {
                const int r0 = rbase + i, r1 = r0 + 1;
                const float4* A0 = (const float4*)(W_ih + (size_t)r0*NI);
                const float4* B0 = (const float4*)(W_hh + (size_t)r0*NH);
                const float4* A1 = (const float4*)(W_ih + (size_t)r1*NI);
                const float4* B1 = (const float4*)(W_hh + (size_t)r1*NH);
                float4 a00=A0[l], a01=A0[l+64], a02=A0[l+128];
                float4 b00=B0[l], b01=B0[l+64];
                float4 a10=A1[l], a11=A1[l+64], a12=A1[l+128];
                float4 b10=B1[l], b11=B1[l+64];
                float v0 = dot4(a00,i0)+dot4(a01,i1)+dot4(a02,i2)
                         + dot4(b00,hv0)+dot4(b01,hv1);
                float v1 = dot4(a10,i0)+dot4(a11,i1)+dot4(a12,i2)
                         + dot4(b10,hv0)+dot4(b11,hv1);
                v0 = wave_red(v0); v1 = wave_red(v1);
                if (l == 0) {
                    cstore(&gatesBuf[r0], v0 + b_ih[r0] + b_hh[r0]);
                    cstore(&gatesBuf[r1], v1 + b_ih[r1] + b_hh[r1]);
                }
            }
        }
        __syncthreads();   // sc1 stores vmcnt-drained

        // ===== S1: gates ready =====
        flag_sync(&cntA[b], 8u*(unsigned)(t+1), tid);

        // ================= P2: LSTM pointwise =================
        if (tid < NH) {
            float ig = sigm(cload(&gatesBuf[tid]));
            float fg = sigm(cload(&gatesBuf[NH + tid]));
            float gg = tanhf(cload(&gatesBuf[2*NH + tid]));
            float og = sigm(cload(&gatesBuf[3*NH + tid]));
            float c = fg*cS[tid] + ig*gg;
            cS[tid] = c;
            hS[tid] = og*tanhf(c);
        }
        __syncthreads();

        // ================= P2b: xi GEMV (replicated) =================
        {
            const float4* h4 = (const float4*)hS;
            float4 hv0 = h4[l], hv1 = h4[l+64];
            for (int row = wv; row < NXI; row += 16) {
                const float4* Wc = (const float4*)(W_xi + (size_t)row*NH);
                float v = dot4(Wc[l], hv0) + dot4(Wc[l+64], hv1);
                v = wave_red(v);
                if (l == 0) xiS[row] = v + b_xi[row];
            }
        }
        __syncthreads();

        // ================= P3: replicated DNC machinery =================
        if (tid < 256)       keys[tid] = tanhf(xiS[tid]);
        else if (tid < 260)  rstr[tid-256] = sftp(xiS[tid]);
        else if (tid < 324)  wkey[tid-260] = tanhf(xiS[tid]);
        else if (tid == 324) sc[0] = sftp(xiS[324]);
        else if (tid < 389)  ers[tid-325] = sigm(xiS[tid]);
        else if (tid < 453)  wvec[tid-389] = tanhf(xiS[tid]);
        else if (tid < 457)  fgte[tid-453] = sigm(xiS[tid]);
        else if (tid == 457) sc[1] = sigm(xiS[457]);
        else if (tid == 458) sc[2] = sigm(xiS[458]);
        else if (tid < 463) {
            int r = tid - 459;
            float a0=xiS[459+3*r], a1=xiS[460+3*r], a2=xiS[461+3*r];
            float mx = fmaxf(a0, fmaxf(a1, a2));
            float e0=expf(a0-mx), e1=expf(a1-mx), e2=expf(a2-mx);
            float si = 1.0f/(e0+e1+e2);
            modes[3*r]=e0*si; modes[3*r+1]=e1*si; modes[3*r+2]=e2*si;
        }
        __syncthreads();

        // E2a: old mem norms + key norms
        if (tid < NM) {
            float ssum = 0.0f;
            for (int w = 0; w < NW; ++w) { float v = mem[tid*MS+w]; ssum += v*v; }
            nmo[tid] = sqrtf(ssum);
        } else if (tid < NM+NR) {
            int r = tid - NM; float ssum = 0.0f;
            for (int w = 0; w < NW; ++w) { float v = keys[r*NW+w]; ssum += v*v; }
            nkey[r] = sqrtf(ssum);
        } else if (tid == NM+NR) {
            float ssum = 0.0f;
            for (int w = 0; w < NW; ++w) { float v = wkey[w]; ssum += v*v; }
            sc[3] = sqrtf(ssum);
        }
        __syncthreads();

        // E2b: usage update
        if (tid < NM) {
            float u = usg[tid];
            u = u + (1.0f - u)*wwO[tid];
            float psi = 1.0f;
            #pragma unroll
            for (int r = 0; r < NR; ++r) psi *= (1.0f - fgte[r]*rwS[r*NM+tid]);
            usg[tid] = u*psi;
        }
        __syncthreads();

        // F1: write-content logits
        if (tid < NM) {
            float d = 0.0f;
            for (int w = 0; w < NW; ++w) d += wkey[w]*mem[tid*MS+w];
            wcw[tid] = d/(sc[3]*nmo[tid] + EPSF) * sc[0];
        }
        __syncthreads();
        // F2: softmax over 128
        if (tid < 64) {
            float v = fmaxf(wcw[tid], wcw[tid+64]);
            #pragma unroll
            for (int o = 32; o > 0; o >>= 1) v = fmaxf(v, __shfl_down(v, o));
            if (tid == 0) red[0] = v;
        }
        __syncthreads();
        if (tid < NM) wcw[tid] = expf(wcw[tid] - red[0]);
        __syncthreads();
        if (tid < 64) {
            float v = wave_red(wcw[tid] + wcw[tid+64]);
            if (tid == 0) red[0] = 1.0f/v;
        }
        __syncthreads();
        if (tid < NM) wcw[tid] *= red[0];
        __syncthreads();

        // G1: u
        if (tid < NM) uu[tid] = 5e-6f + (1.0f - 5e-6f)*usg[tid];
        __syncthreads();
        // G2: stable rank
        if (tid < NM) {
            float um = uu[tid]; int rk = 0;
            for (int j = 0; j < NM; ++j) {
                float uj = uu[j];
                rk += (uj < um) || (uj == um && j < tid);
            }
            rnk[tid] = rk;
            su[rk] = um;
        }
        __syncthreads();
        // G3: product scan (wave 0)
        if (tid < 64) {
            float a = su[tid], bb = su[64+tid];
            #pragma unroll
            for (int o = 1; o < 64; o <<= 1) {
                float ta = __shfl_up(a, o);
                float tb = __shfl_up(bb, o);
                if (tid >= o) { a *= ta; bb *= tb; }
            }
            float P0 = __shfl(a, 63);
            cum[tid] = a;
            cum[64+tid] = P0*bb;
        }
        __syncthreads();
        // G4: alloc + write weighting
        if (tid < NM) {
            int rk = rnk[tid];
            float excl = (rk == 0) ? 1.0f : cum[rk-1];
            float al = (1.0f - uu[tid])*excl;
            wwN[tid] = sc[2]*(sc[1]*al + (1.0f - sc[1])*wcw[tid]);
        }
        __syncthreads();
        // G5: sum(wwN)
        if (tid < 64) {
            float v = wave_red(wwN[tid] + wwN[tid+64]);
            if (tid == 0) sc[4] = v;
        }
        __syncthreads();

        // H1: mem erase/write (replicated) + OWN link slice in-place update
        for (int e = tid; e < NM*NW; e += TPB) {
            int m = e >> 6, w = e & 63;
            float wm = wwN[m];
            mem[m*MS+w] = mem[m*MS+w]*(1.0f - wm*ers[w]) + wm*wvec[w];
        }
        for (int e = tid; e < SL*NM; e += TPB) {
            int ii = e >> 7, j = e & 127;
            int i = s*SL + ii;
            float nl = (i == j) ? 0.0f
                     : (1.0f - wwN[i] - wwN[j])*lkS[e] + wwN[i]*prc[j];
            lkS[e] = nl;
        }
        __syncthreads();
        // H2: new mem norms
        if (tid < NM) {
            float ssum = 0.0f;
            for (int w = 0; w < NW; ++w) { float v = mem[tid*MS+w]; ssum += v*v; }
            nmn[tid] = sqrtf(ssum);
        }
        __syncthreads();
        // H3: precedence
        if (tid < NM) prc[tid] = (1.0f - sc[4])*prc[tid] + wwN[tid];
        __syncthreads();

        // I: read-content logits + per-r softmax (replicated)
        if (tid < NR*NM) {
            int r = tid >> 7, m = tid & 127;
            float d = 0.0f;
            for (int w = 0; w < NW; ++w) d += keys[r*NW+w]*mem[m*MS+w];
            ccw[tid] = d/(nkey[r]*nmn[m] + EPSF) * rstr[r];
        }
        __syncthreads();
        if (tid < 256) {
            int r = tid >> 6, ll = tid & 63;
            float v = fmaxf(ccw[r*NM+ll], ccw[r*NM+ll+64]);
            #pragma unroll
            for (int o = 32; o > 0; o >>= 1) v = fmaxf(v, __shfl_down(v, o));
            if (ll == 0) red[r] = v;
        }
        __syncthreads();
        if (tid < NR*NM) ccw[tid] = expf(ccw[tid] - red[tid>>7]);
        __syncthreads();
        if (tid < 256) {
            int r = tid >> 6, ll = tid & 63;
            float v = wave_red(ccw[r*NM+ll] + ccw[r*NM+ll+64]);
            if (ll == 0) red[4+r] = 1.0f/v;
        }
        __syncthreads();
        if (tid < NR*NM) ccw[tid] *= red[4+(tid>>7)];
        __syncthreads();

        // J1: fwd for OWN 16 m's (rows of own slice): 64 outputs, 16 waves
        {
            for (int q = 0; q < 4; ++q) {
                const int p = wv*4 + q;          // 0..63
                const int r = p >> 4, mi = p & 15;
                float partial = lkS[mi*NM + l]*rwS[r*NM + l]
                              + lkS[mi*NM + 64 + l]*rwS[r*NM + 64 + l];
                partial = wave_red(partial);
                if (l == 0) cstore(&fwdBuf[r*NM + s*SL + mi], partial);
            }
        }
        // J2: bwd partials over OWN rows: bwd_p[r][m] = sum_{i in slice}
        if (tid < NR*NM) {
            const int r = tid >> 7, m = tid & 127;
            float acc = 0.0f;
            #pragma unroll
            for (int i = 0; i < SL; ++i)
                acc += lkS[i*NM + m]*rwS[r*NM + s*SL + i];
            cstore(&bwdBuf[tid], acc);
        }
        __syncthreads();   // drain sc1 stores

        // ===== S2: fwd + bwd partials ready =====
        flag_sync(&cntB[b], 8u*(unsigned)(t+1), tid);

        // J3: reduce partials + mode mix -> new rw (replicated)
        float rwnew = 0.0f;
        if (tid < NR*NM) {
            const int r = tid >> 7;
            float bw = 0.0f;
            #pragma unroll
            for (int sp = 0; sp < 8; ++sp)
                bw += cload(&bwdBufB[sp*NR*NM + tid]);
            float fw = cload(&fwdBuf[tid]);
            rwnew = modes[3*r]*bw + modes[3*r+1]*fw + modes[3*r+2]*ccw[tid];
        }
        __syncthreads();
        if (tid < NR*NM) rwS[tid] = rwnew;
        __syncthreads();

        // K: read vectors (replicated)
        if (tid < NR*NW) {
            int r = tid >> 6, w = tid & 63;
            float ssum = 0.0f;
            for (int m = 0; m < NM; ++m) ssum += rwS[r*NM+m]*mem[m*MS+w];
            rv[tid] = ssum;
        }
        __syncthreads();

        // ================= out GEMV slice (64 rows/block) ==================
        {
            const float4* h4  = (const float4*)hS;
            const float4* rv4 = (const float4*)rv;
            float4 hv0 = h4[l], hv1 = h4[l+64], rvv = rv4[l];
            const int rbase = s*64 + wv*4;
            for (int i = 0; i < 4; ++i) {
                const int row = rbase + i;
                const float4* Wo = (const float4*)(W_o + (size_t)row*NI);
                float v = dot4(Wo[l],hv0) + dot4(Wo[l+64],hv1) + dot4(Wo[l+128],rvv);
                v = wave_red(v);
                if (l == 0) out[((size_t)b*NT + t)*NH + row] = v + b_o[row];
            }
        }
        __syncthreads();

        // M: carries
        if (tid < NR*NW) inp[NH + tid] = rv[tid];
        else if (tid < NR*NW + NM) wwO[tid - NR*NW] = wwN[tid - NR*NW];
        __syncthreads();
    }
}

extern "C" void kernel_launch(void* const* d_in, const int* in_sizes, int n_in,
                              void* d_out, int out_size, void* d_ws, size_t ws_size,
                              hipStream_t stream) {
    (void)in_sizes; (void)n_in; (void)out_size; (void)ws_size;
    const float* x    = (const float*)d_in[0];
    const float* W_ih = (const float*)d_in[1];
    const float* W_hh = (const float*)d_in[2];
    const float* b_ih = (const float*)d_in[3];
    const float* b_hh = (const float*)d_in[4];
    const float* W_xi = (const float*)d_in[5];
    const float* b_xi = (const float*)d_in[6];
    const float* W_o  = (const float*)d_in[7];
    const float* b_o  = (const float*)d_in[8];
    float* out = (float*)d_out;
    float* ws  = (float*)d_ws;

    void* args[] = { (void*)&x, (void*)&W_ih, (void*)&W_hh, (void*)&b_ih,
                     (void*)&b_hh, (void*)&W_xi, (void*)&b_xi, (void*)&W_o,
                     (void*)&b_o, (void*)&out, (void*)&ws };
    hipLaunchCooperativeKernel((void*)dnc_sliced, dim3(NBLK), dim3(TPB),
                               args, 0, stream);
}

// Round 9
// 6560.085 us; speedup vs baseline: 1.4164x; 1.1306x over previous
//
#include <hip/hip_runtime.h>
#include <math.h>

#define TPB 1024
#define NBLK 256
#define NBATCH 32
#define NT 64
#define NH 512
#define NM 128
#define NR 4
#define NW 64
#define NI 768          // controller input size (H + R*W)
#define NXI 471         // interface vector size
#define NG 2048         // gate rows
#define SL 16           // link rows per slice (128/8)
#define EPSF 1e-6f
#define MS 65           // mem row stride (+1 pad)

// ws layout (float offsets); counters padded to 64B (16 floats)
#define WS_LINK  0                                    // [32][8][16*128] private slices
#define WS_GATES (WS_LINK + NBATCH*8*SL*NM)           // [32][2][2048] parity dbuf
#define WS_FWD   (WS_GATES + NBATCH*2*NG)             // [32][512]
#define WS_BWDP  (WS_FWD + NBATCH*NR*NM)              // [32][8][512]
#define WS_CNTA  (WS_BWDP + NBATCH*8*NR*NM)           // 32 x 16-padded uints
#define WS_CNTB  (WS_CNTA + NBATCH*16)                // 32 x 16-padded uints
#define WS_POOL  (WS_CNTB + NBATCH*16)                // 8 x 16-padded uints
#define WS_ZEND  (WS_POOL + 8*16)

// HW_REG_XCC_ID = 20, offset 0, size 4  ->  imm = 20 | (0<<6) | ((4-1)<<11)
#define XCC_GETREG_IMM (20 | (3 << 11))

__device__ __forceinline__ float sigm(float x){ return 1.0f/(1.0f+expf(-x)); }
__device__ __forceinline__ float sftp(float x){ return fmaxf(x,0.0f)+log1pf(expf(-fabsf(x))); }
__device__ __forceinline__ float dot4(float4 a, float4 b){
    return a.x*b.x + a.y*b.y + a.z*b.z + a.w*b.w;
}
__device__ __forceinline__ float wave_red(float v){
    #pragma unroll
    for (int o = 32; o > 0; o >>= 1) v += __shfl_down(v, o);
    return v;
}
// cross-XCD coherent accessors (LLC, bypass L2, no invalidates)
__device__ __forceinline__ void cstore(float* p, float v){
    __hip_atomic_store(p, v, __ATOMIC_RELAXED, __HIP_MEMORY_SCOPE_AGENT);
}
__device__ __forceinline__ float cload(const float* p){
    return __hip_atomic_load(p, __ATOMIC_RELAXED, __HIP_MEMORY_SCOPE_AGENT);
}
__device__ __forceinline__ void flag_sync(unsigned int* c, unsigned int target,
                                          int tid){
    if (tid == 0) {
        __hip_atomic_fetch_add(c, 1u, __ATOMIC_RELEASE, __HIP_MEMORY_SCOPE_AGENT);
        while (__hip_atomic_load(c, __ATOMIC_RELAXED,
                                 __HIP_MEMORY_SCOPE_AGENT) < target)
            __builtin_amdgcn_s_sleep(8);
    }
    __syncthreads();
}

__global__ void dnc_zero(float* ws){
    unsigned int* z = (unsigned int*)(ws + WS_CNTA);
    const int n = WS_ZEND - WS_CNTA;
    for (int e = threadIdx.x; e < n; e += 256) z[e] = 0u;
}

__global__ __launch_bounds__(TPB) void dnc_xcd(
    const float* __restrict__ x, const float* __restrict__ W_ih,
    const float* __restrict__ W_hh, const float* __restrict__ b_ih,
    const float* __restrict__ b_hh, const float* __restrict__ W_xi,
    const float* __restrict__ b_xi, const float* __restrict__ W_o,
    const float* __restrict__ b_o, float* __restrict__ out,
    float* __restrict__ ws)
{
    // -------- per-block private replicated state --------
    __shared__ float mem[NM*MS];
    __shared__ __align__(16) float hS[NH];
    __shared__ float cS[NH];
    __shared__ float rwS[NR*NM];
    __shared__ float wwO[NM], wwN[NM];
    __shared__ float usg[NM], prc[NM];
    __shared__ __align__(16) float inp[NI];      // [x_t | last_read]
    __shared__ float xiS[NXI+1];
    __shared__ float keys[NR*NW];
    __shared__ float wkey[NW], ers[NW], wvec[NW];
    __shared__ float rstr[NR], fgte[NR], modes[NR*3], nkey[NR];
    __shared__ float sc[8];               // 0:wstr 1:ag 2:wg 3:|wkey| 4:sum(ww)
    __shared__ float nmo[NM], nmn[NM];
    __shared__ float wcw[NM], uu[NM], su[NM], cum[NM];
    __shared__ int   rnk[NM];
    __shared__ float ccw[NR*NM];
    __shared__ __align__(16) float rv[NR*NW];
    __shared__ float red[8];
    __shared__ int   bS, sS;

    const int tid = threadIdx.x;
    const int wv  = tid >> 6;             // wave id 0..15
    const int l   = tid & 63;             // lane

    // -------- claim (batch, slice) from my physical XCD's pool --------
    unsigned int* __restrict__ pool = (unsigned int*)(ws + WS_POOL);
    {
        unsigned int myxcd = __builtin_amdgcn_s_getreg(XCC_GETREG_IMM) & 7u;
        if (tid == 0) {
            int bb = -1, ss = -1;
            for (int k = 0; k < 8 && bb < 0; ++k) {
                int p = (int)((myxcd + (unsigned)k) & 7u);
                unsigned int r = __hip_atomic_fetch_add(&pool[p*16], 1u,
                                     __ATOMIC_RELAXED, __HIP_MEMORY_SCOPE_AGENT);
                if (r < 32u) { bb = (int)r; ss = p; }
            }
            bS = bb; sS = ss;             // guaranteed success (pigeonhole)
        }
    }
    __syncthreads();
    const int b = bS;
    const int s = sS;

    float* __restrict__ lkS     = ws + WS_LINK + ((size_t)b*8 + s)*SL*NM; // PRIVATE
    float* __restrict__ fwdBuf  = ws + WS_FWD  + (size_t)b*NR*NM;
    float* __restrict__ bwdBuf  = ws + WS_BWDP + ((size_t)b*8 + s)*NR*NM;
    float* __restrict__ bwdBufB = ws + WS_BWDP + (size_t)b*8*NR*NM;
    unsigned int* __restrict__ cntA = (unsigned int*)(ws + WS_CNTA) + b*16;
    unsigned int* __restrict__ cntB = (unsigned int*)(ws + WS_CNTB) + b*16;

    // -------- init (own data only; no cross-block deps before step-0 flags) --
    for (int e = tid; e < SL*NM; e += TPB) lkS[e] = 0.0f;
    for (int e = tid; e < NM*NW; e += TPB) mem[(e>>6)*MS + (e&63)] = EPSF;
    for (int e = tid; e < NH; e += TPB){ hS[e]=0.0f; cS[e]=0.0f; }
    for (int e = tid; e < NR*NM; e += TPB) rwS[e]=0.0f;
    for (int e = tid; e < NM; e += TPB){ wwO[e]=0.0f; usg[e]=0.0f; prc[e]=0.0f; }
    for (int e = tid; e < NR*NW; e += TPB) inp[NH+e]=0.0f;
    __syncthreads();

    for (int t = 0; t < NT; ++t) {
        float* __restrict__ gatesBuf = ws + WS_GATES + ((size_t)b*2 + (t & 1))*NG;

        // ================= P1: x_t load + gates GEMV slice =================
        if (tid < NH) inp[tid] = x[((size_t)b*NT + t)*NH + tid];
        __syncthreads();
        {
            const float4* inp4 = (const float4*)inp;
            const float4* h4   = (const float4*)hS;
            float4 i0 = inp4[l], i1 = inp4[l+64], i2 = inp4[l+128];
            float4 hv0 = h4[l], hv1 = h4[l+64];
            const int rbase = s*256 + wv*16;
            for (int i = 0; i < 16; i += 2) {
                const int r0 = rbase + i, r1 = r0 + 1;
                const float4* A0 = (const float4*)(W_ih + (size_t)r0*NI);
                const float4* B0 = (const float4*)(W_hh + (size_t)r0*NH);
                const float4* A1 = (const float4*)(W_ih + (size_t)r1*NI);
                const float4* B1 = (const float4*)(W_hh + (size_t)r1*NH);
                float4 a00=A0[l], a01=A0[l+64], a02=A0[l+128];
                float4 b00=B0[l], b01=B0[l+64];
                float4 a10=A1[l], a11=A1[l+64], a12=A1[l+128];
                float4 b10=B1[l], b11=B1[l+64];
                float v0 = dot4(a00,i0)+dot4(a01,i1)+dot4(a02,i2)
                         + dot4(b00,hv0)+dot4(b01,hv1);
                float v1 = dot4(a10,i0)+dot4(a11,i1)+dot4(a12,i2)
                         + dot4(b10,hv0)+dot4(b11,hv1);
                v0 = wave_red(v0); v1 = wave_red(v1);
                if (l == 0) {
                    cstore(&gatesBuf[r0], v0 + b_ih[r0] + b_hh[r0]);
                    cstore(&gatesBuf[r1], v1 + b_ih[r1] + b_hh[r1]);
                }
            }
        }
        __syncthreads();   // sc1 stores vmcnt-drained

        // ===== S1: gates ready =====
        flag_sync(cntA, 8u*(unsigned)(t+1), tid);

        // ================= P2: LSTM pointwise =================
        if (tid < NH) {
            float ig = sigm(cload(&gatesBuf[tid]));
            float fg = sigm(cload(&gatesBuf[NH + tid]));
            float gg = tanhf(cload(&gatesBuf[2*NH + tid]));
            float og = sigm(cload(&gatesBuf[3*NH + tid]));
            float c = fg*cS[tid] + ig*gg;
            cS[tid] = c;
            hS[tid] = og*tanhf(c);
        }
        __syncthreads();

        // ================= P2b: xi GEMV (replicated) =================
        {
            const float4* h4 = (const float4*)hS;
            float4 hv0 = h4[l], hv1 = h4[l+64];
            for (int row = wv; row < NXI; row += 16) {
                const float4* Wc = (const float4*)(W_xi + (size_t)row*NH);
                float v = dot4(Wc[l], hv0) + dot4(Wc[l+64], hv1);
                v = wave_red(v);
                if (l == 0) xiS[row] = v + b_xi[row];
            }
        }
        __syncthreads();

        // ================= P3: replicated DNC machinery =================
        if (tid < 256)       keys[tid] = tanhf(xiS[tid]);
        else if (tid < 260)  rstr[tid-256] = sftp(xiS[tid]);
        else if (tid < 324)  wkey[tid-260] = tanhf(xiS[tid]);
        else if (tid == 324) sc[0] = sftp(xiS[324]);
        else if (tid < 389)  ers[tid-325] = sigm(xiS[tid]);
        else if (tid < 453)  wvec[tid-389] = tanhf(xiS[tid]);
        else if (tid < 457)  fgte[tid-453] = sigm(xiS[tid]);
        else if (tid == 457) sc[1] = sigm(xiS[457]);
        else if (tid == 458) sc[2] = sigm(xiS[458]);
        else if (tid < 463) {
            int r = tid - 459;
            float a0=xiS[459+3*r], a1=xiS[460+3*r], a2=xiS[461+3*r];
            float mx = fmaxf(a0, fmaxf(a1, a2));
            float e0=expf(a0-mx), e1=expf(a1-mx), e2=expf(a2-mx);
            float si = 1.0f/(e0+e1+e2);
            modes[3*r]=e0*si; modes[3*r+1]=e1*si; modes[3*r+2]=e2*si;
        }
        __syncthreads();

        // E2a: old mem norms + key norms
        if (tid < NM) {
            float ssum = 0.0f;
            for (int w = 0; w < NW; ++w) { float v = mem[tid*MS+w]; ssum += v*v; }
            nmo[tid] = sqrtf(ssum);
        } else if (tid < NM+NR) {
            int r = tid - NM; float ssum = 0.0f;
            for (int w = 0; w < NW; ++w) { float v = keys[r*NW+w]; ssum += v*v; }
            nkey[r] = sqrtf(ssum);
        } else if (tid == NM+NR) {
            float ssum = 0.0f;
            for (int w = 0; w < NW; ++w) { float v = wkey[w]; ssum += v*v; }
            sc[3] = sqrtf(ssum);
        }
        __syncthreads();

        // E2b: usage update
        if (tid < NM) {
            float u = usg[tid];
            u = u + (1.0f - u)*wwO[tid];
            float psi = 1.0f;
            #pragma unroll
            for (int r = 0; r < NR; ++r) psi *= (1.0f - fgte[r]*rwS[r*NM+tid]);
            usg[tid] = u*psi;
        }
        __syncthreads();

        // F1: write-content logits
        if (tid < NM) {
            float d = 0.0f;
            for (int w = 0; w < NW; ++w) d += wkey[w]*mem[tid*MS+w];
            wcw[tid] = d/(sc[3]*nmo[tid] + EPSF) * sc[0];
        }
        __syncthreads();
        // F2: softmax over 128
        if (tid < 64) {
            float v = fmaxf(wcw[tid], wcw[tid+64]);
            #pragma unroll
            for (int o = 32; o > 0; o >>= 1) v = fmaxf(v, __shfl_down(v, o));
            if (tid == 0) red[0] = v;
        }
        __syncthreads();
        if (tid < NM) wcw[tid] = expf(wcw[tid] - red[0]);
        __syncthreads();
        if (tid < 64) {
            float v = wave_red(wcw[tid] + wcw[tid+64]);
            if (tid == 0) red[0] = 1.0f/v;
        }
        __syncthreads();
        if (tid < NM) wcw[tid] *= red[0];
        __syncthreads();

        // G1: u
        if (tid < NM) uu[tid] = 5e-6f + (1.0f - 5e-6f)*usg[tid];
        __syncthreads();
        // G2: stable rank
        if (tid < NM) {
            float um = uu[tid]; int rk = 0;
            for (int j = 0; j < NM; ++j) {
                float uj = uu[j];
                rk += (uj < um) || (uj == um && j < tid);
            }
            rnk[tid] = rk;
            su[rk] = um;
        }
        __syncthreads();
        // G3: product scan (wave 0)
        if (tid < 64) {
            float a = su[tid], bb = su[64+tid];
            #pragma unroll
            for (int o = 1; o < 64; o <<= 1) {
                float ta = __shfl_up(a, o);
                float tb = __shfl_up(bb, o);
                if (tid >= o) { a *= ta; bb *= tb; }
            }
            float P0 = __shfl(a, 63);
            cum[tid] = a;
            cum[64+tid] = P0*bb;
        }
        __syncthreads();
        // G4: alloc + write weighting
        if (tid < NM) {
            int rk = rnk[tid];
            float excl = (rk == 0) ? 1.0f : cum[rk-1];
            float al = (1.0f - uu[tid])*excl;
            wwN[tid] = sc[2]*(sc[1]*al + (1.0f - sc[1])*wcw[tid]);
        }
        __syncthreads();
        // G5: sum(wwN)
        if (tid < 64) {
            float v = wave_red(wwN[tid] + wwN[tid+64]);
            if (tid == 0) sc[4] = v;
        }
        __syncthreads();

        // H1: mem erase/write (replicated) + OWN link slice in-place update
        for (int e = tid; e < NM*NW; e += TPB) {
            int m = e >> 6, w = e & 63;
            float wm = wwN[m];
            mem[m*MS+w] = mem[m*MS+w]*(1.0f - wm*ers[w]) + wm*wvec[w];
        }
        for (int e = tid; e < SL*NM; e += TPB) {
            int ii = e >> 7, j = e & 127;
            int i = s*SL + ii;
            float nl = (i == j) ? 0.0f
                     : (1.0f - wwN[i] - wwN[j])*lkS[e] + wwN[i]*prc[j];
            lkS[e] = nl;
        }
        __syncthreads();
        // H2: new mem norms
        if (tid < NM) {
            float ssum = 0.0f;
            for (int w = 0; w < NW; ++w) { float v = mem[tid*MS+w]; ssum += v*v; }
            nmn[tid] = sqrtf(ssum);
        }
        __syncthreads();
        // H3: precedence
        if (tid < NM) prc[tid] = (1.0f - sc[4])*prc[tid] + wwN[tid];
        __syncthreads();

        // I: read-content logits + per-r softmax (replicated)
        if (tid < NR*NM) {
            int r = tid >> 7, m = tid & 127;
            float d = 0.0f;
            for (int w = 0; w < NW; ++w) d += keys[r*NW+w]*mem[m*MS+w];
            ccw[tid] = d/(nkey[r]*nmn[m] + EPSF) * rstr[r];
        }
        __syncthreads();
        if (tid < 256) {
            int r = tid >> 6, ll = tid & 63;
            float v = fmaxf(ccw[r*NM+ll], ccw[r*NM+ll+64]);
            #pragma unroll
            for (int o = 32; o > 0; o >>= 1) v = fmaxf(v, __shfl_down(v, o));
            if (ll == 0) red[r] = v;
        }
        __syncthreads();
        if (tid < NR*NM) ccw[tid] = expf(ccw[tid] - red[tid>>7]);
        __syncthreads();
        if (tid < 256) {
            int r = tid >> 6, ll = tid & 63;
            float v = wave_red(ccw[r*NM+ll] + ccw[r*NM+ll+64]);
            if (ll == 0) red[4+r] = 1.0f/v;
        }
        __syncthreads();
        if (tid < NR*NM) ccw[tid] *= red[4+(tid>>7)];
        __syncthreads();

        // J1: fwd for OWN 16 m's
        {
            for (int q = 0; q < 4; ++q) {
                const int p = wv*4 + q;          // 0..63
                const int r = p >> 4, mi = p & 15;
                float partial = lkS[mi*NM + l]*rwS[r*NM + l]
                              + lkS[mi*NM + 64 + l]*rwS[r*NM + 64 + l];
                partial = wave_red(partial);
                if (l == 0) cstore(&fwdBuf[r*NM + s*SL + mi], partial);
            }
        }
        // J2: bwd partials over OWN rows
        if (tid < NR*NM) {
            const int r = tid >> 7, m = tid & 127;
            float acc = 0.0f;
            #pragma unroll
            for (int i = 0; i < SL; ++i)
                acc += lkS[i*NM + m]*rwS[r*NM + s*SL + i];
            cstore(&bwdBuf[tid], acc);
        }
        __syncthreads();   // drain sc1 stores

        // ===== S2: fwd + bwd partials ready =====
        flag_sync(cntB, 8u*(unsigned)(t+1), tid);

        // J3: reduce partials + mode mix -> new rw (replicated)
        float rwnew = 0.0f;
        if (tid < NR*NM) {
            const int r = tid >> 7;
            float bw = 0.0f;
            #pragma unroll
            for (int sp = 0; sp < 8; ++sp)
                bw += cload(&bwdBufB[sp*NR*NM + tid]);
            float fw = cload(&fwdBuf[tid]);
            rwnew = modes[3*r]*bw + modes[3*r+1]*fw + modes[3*r+2]*ccw[tid];
        }
        __syncthreads();
        if (tid < NR*NM) rwS[tid] = rwnew;
        __syncthreads();

        // K: read vectors (replicated)
        if (tid < NR*NW) {
            int r = tid >> 6, w = tid & 63;
            float ssum = 0.0f;
            for (int m = 0; m < NM; ++m) ssum += rwS[r*NM+m]*mem[m*MS+w];
            rv[tid] = ssum;
        }
        __syncthreads();

        // ================= out GEMV slice (64 rows/block) ==================
        {
            const float4* h4  = (const float4*)hS;
            const float4* rv4 = (const float4*)rv;
            float4 hv0 = h4[l], hv1 = h4[l+64], rvv = rv4[l];
            const int rbase = s*64 + wv*4;
            for (int i = 0; i < 4; ++i) {
                const int row = rbase + i;
                const float4* Wo = (const float4*)(W_o + (size_t)row*NI);
                float v = dot4(Wo[l],hv0) + dot4(Wo[l+64],hv1) + dot4(Wo[l+128],rvv);
                v = wave_red(v);
                if (l == 0) out[((size_t)b*NT + t)*NH + row] = v + b_o[row];
            }
        }
        __syncthreads();

        // M: carries
        if (tid < NR*NW) inp[NH + tid] = rv[tid];
        else if (tid < NR*NW + NM) wwO[tid - NR*NW] = wwN[tid - NR*NW];
        __syncthreads();
    }
}

extern "C" void kernel_launch(void* const* d_in, const int* in_sizes, int n_in,
                              void* d_out, int out_size, void* d_ws, size_t ws_size,
                              hipStream_t stream) {
    (void)in_sizes; (void)n_in; (void)out_size; (void)ws_size;
    const float* x    = (const float*)d_in[0];
    const float* W_ih = (const float*)d_in[1];
    const float* W_hh = (const float*)d_in[2];
    const float* b_ih = (const float*)d_in[3];
    const float* b_hh = (const float*)d_in[4];
    const float* W_xi = (const float*)d_in[5];
    const float* b_xi = (const float*)d_in[6];
    const float* W_o  = (const float*)d_in[7];
    const float* b_o  = (const float*)d_in[8];
    float* out = (float*)d_out;
    float* ws  = (float*)d_ws;

    dnc_zero<<<1, 256, 0, stream>>>(ws);

    void* args[] = { (void*)&x, (void*)&W_ih, (void*)&W_hh, (void*)&b_ih,
                     (void*)&b_hh, (void*)&W_xi, (void*)&b_xi, (void*)&W_o,
                     (void*)&b_o, (void*)&out, (void*)&ws };
    hipLaunchCooperativeKernel((void*)dnc_xcd, dim3(NBLK), dim3(TPB),
                               args, 0, stream);
}

// Round 11
// 5830.626 us; speedup vs baseline: 1.5936x; 1.1251x over previous
//
#include <hip/hip_runtime.h>
#include <math.h>

#define TPB 1024
#define NBLK 256
#define NBATCH 32
#define NT 64
#define NH 512
#define NM 128
#define NR 4
#define NW 64
#define NI 768          // controller input size (H + R*W)
#define NXI 471         // interface vector size
#define NG 2048         // gate rows
#define EPSF 1e-6f
#define MS 65           // mem row stride (+1 pad)

// roles: [0,32) state | [32,160) gates(128) | [160,192) xi(32) | [192,256) out(64)

// ws layout (float offsets). pub* are parity double-buffered.
#define WS_LINK  0                                 // [32][128*128]
#define WS_PUBH  (WS_LINK + NBATCH*NM*NM)          // [2][32][512]
#define WS_PUBRV (WS_PUBH + 2*NBATCH*NH)           // [2][32][256]
#define WS_PUBG  (WS_PUBRV + 2*NBATCH*NR*NW)       // [2][32][2048]
#define WS_PUBXI (WS_PUBG + 2*NBATCH*NG)           // [2][32][480]
#define WS_FLAGS (WS_PUBXI + 2*NBATCH*480)         // 5 x 16-padded uints
#define F_S  0    // state: h published   (init + per step)
#define F_S2 16   // state: rv published  (init + per step)
#define F_G  32   // gates ready
#define F_X  48   // xi ready
#define F_O  64   // out done

__device__ __forceinline__ float sigm(float x){ return 1.0f/(1.0f+expf(-x)); }
__device__ __forceinline__ float sftp(float x){ return fmaxf(x,0.0f)+log1pf(expf(-fabsf(x))); }
__device__ __forceinline__ float dot4(float4 a, float4 b){
    return a.x*b.x + a.y*b.y + a.z*b.z + a.w*b.w;
}
__device__ __forceinline__ float wave_red(float v){
    #pragma unroll
    for (int o = 32; o > 0; o >>= 1) v += __shfl_down(v, o);
    return v;
}
// LLC-coherent accessors (sc1: bypass L2, no invalidates) — proven r7-r9
__device__ __forceinline__ void cstore(float* p, float v){
    __hip_atomic_store(p, v, __ATOMIC_RELAXED, __HIP_MEMORY_SCOPE_AGENT);
}
__device__ __forceinline__ float cload(const float* p){
    return __hip_atomic_load(p, __ATOMIC_RELAXED, __HIP_MEMORY_SCOPE_AGENT);
}
__device__ __forceinline__ void fwait(unsigned int* c, unsigned int target,
                                      int tid){
    if (tid == 0) {
        while (__hip_atomic_load(c, __ATOMIC_RELAXED,
                                 __HIP_MEMORY_SCOPE_AGENT) < target)
            __builtin_amdgcn_s_sleep(2);
    }
    __syncthreads();
}
__device__ __forceinline__ void fbump(unsigned int* c, int tid){
    __syncthreads();   // drain all waves' stores first
    if (tid == 0)
        __hip_atomic_fetch_add(c, 1u, __ATOMIC_RELEASE,
                               __HIP_MEMORY_SCOPE_AGENT);
}

__global__ void dnc_zero(float* ws){
    unsigned int* z = (unsigned int*)(ws + WS_FLAGS);
    if (threadIdx.x < 80) z[threadIdx.x] = 0u;
}

// ---- pooled LDS offsets (floats); S[13504] = 54,016 B ----
#define O_MEM 0
#define O_H   8320
#define O_C   8832
#define O_RW  9344
#define O_WWO 9856
#define O_WWN 9984
#define O_USG 10112
#define O_PRC 10240
#define O_XI  10368
#define O_KEY 10840
#define O_WK  11096
#define O_ER  11160
#define O_WV  11224
#define O_RS  11288
#define O_FG  11292
#define O_MD  11296
#define O_NK  11308
#define O_SC  11312
#define O_NMO 11320
#define O_NMN 11448
#define O_WCW 11576
#define O_UU  11704
#define O_SU  11832
#define O_CUM 11960
#define O_RNK 12088
#define O_CCW 12216
#define O_FWD 12728
#define O_RV  13240
#define O_RED 13496
#define S_SZ  13504

__global__ __launch_bounds__(TPB) void dnc_gemm(
    const float* __restrict__ x, const float* __restrict__ W_ih,
    const float* __restrict__ W_hh, const float* __restrict__ b_ih,
    const float* __restrict__ b_hh, const float* __restrict__ W_xi,
    const float* __restrict__ b_xi, const float* __restrict__ W_o,
    const float* __restrict__ b_o, float* __restrict__ out,
    float* __restrict__ ws)
{
    __shared__ __align__(16) float S[S_SZ];

    const int tid = threadIdx.x;
    const int wv  = tid >> 6;
    const int l   = tid & 63;
    const int bid = blockIdx.x;

    float* __restrict__ pubH  = ws + WS_PUBH;
    float* __restrict__ pubRV = ws + WS_PUBRV;
    float* __restrict__ pubG  = ws + WS_PUBG;
    float* __restrict__ pubXI = ws + WS_PUBXI;
    unsigned int* __restrict__ flags = (unsigned int*)(ws + WS_FLAGS);

    if (bid < NBATCH) {
        // ========================= STATE block =========================
        const int b = bid;
        float* __restrict__ lk = ws + WS_LINK + (size_t)b*NM*NM;
        float* mem = S+O_MEM;  float* hS = S+O_H;   float* cS = S+O_C;
        float* rwS = S+O_RW;   float* wwO = S+O_WWO; float* wwN = S+O_WWN;
        float* usg = S+O_USG;  float* prc = S+O_PRC; float* xiS = S+O_XI;
        float* keys = S+O_KEY; float* wkey = S+O_WK; float* ers = S+O_ER;
        float* wvec = S+O_WV;  float* rstr = S+O_RS; float* fgte = S+O_FG;
        float* modes = S+O_MD; float* nkey = S+O_NK; float* sc = S+O_SC;
        float* nmo = S+O_NMO;  float* nmn = S+O_NMN; float* wcw = S+O_WCW;
        float* uu = S+O_UU;    float* su = S+O_SU;   float* cum = S+O_CUM;
        int*   rnk = (int*)(S+O_RNK);
        float* ccw = S+O_CCW;  float* fwdT = S+O_FWD; float* rv = S+O_RV;
        float* red = S+O_RED;

        for (int e = tid; e < NM*NM; e += TPB) lk[e] = 0.0f;
        for (int e = tid; e < NM*NW; e += TPB) mem[(e>>6)*MS + (e&63)] = EPSF;
        for (int e = tid; e < NH; e += TPB){ hS[e]=0.0f; cS[e]=0.0f; }
        for (int e = tid; e < NR*NM; e += TPB) rwS[e]=0.0f;
        for (int e = tid; e < NM; e += TPB){ wwO[e]=0.0f; usg[e]=0.0f; prc[e]=0.0f; }
        // publish h_{-1}=0, rv_{-1}=0 into parity 1 (gates step 0 reads parity 1)
        if (tid < NH)    cstore(&pubH[(size_t)1*NBATCH*NH + b*NH + tid], 0.0f);
        if (tid < NR*NW) cstore(&pubRV[(size_t)1*NBATCH*NR*NW + b*NR*NW + tid], 0.0f);
        fbump(&flags[F_S], tid);
        fbump(&flags[F_S2], tid);

        for (int t = 0; t < NT; ++t) {
            const int par = t & 1;
            // gates for step t ready
            fwait(&flags[F_G], 128u*(unsigned)(t+1), tid);
            {
                const float* gb = pubG + ((size_t)par*NBATCH + b)*NG;
                if (tid < NH) {
                    float ig = sigm(cload(&gb[tid]));
                    float fg = sigm(cload(&gb[NH + tid]));
                    float gg = tanhf(cload(&gb[2*NH + tid]));
                    float og = sigm(cload(&gb[3*NH + tid]));
                    float c = fg*cS[tid] + ig*gg;
                    cS[tid] = c;
                    hS[tid] = og*tanhf(c);
                }
            }
            __syncthreads();
            // before overwriting h_{t-2}/rv_{t-2}: out step t-2 must be done
            if (t >= 2) fwait(&flags[F_O], 64u*(unsigned)(t-1), tid);
            if (tid < NH) cstore(&pubH[(size_t)par*NBATCH*NH + b*NH + tid], hS[tid]);
            fbump(&flags[F_S], tid);

            // xi for step t ready
            fwait(&flags[F_X], 32u*(unsigned)(t+1), tid);
            if (tid < NXI) xiS[tid] = cload(&pubXI[(size_t)par*NBATCH*480 + b*480 + tid]);
            __syncthreads();

            // E1: unpack interface
            if (tid < 256)       keys[tid] = tanhf(xiS[tid]);
            else if (tid < 260)  rstr[tid-256] = sftp(xiS[tid]);
            else if (tid < 324)  wkey[tid-260] = tanhf(xiS[tid]);
            else if (tid == 324) sc[0] = sftp(xiS[324]);
            else if (tid < 389)  ers[tid-325] = sigm(xiS[tid]);
            else if (tid < 453)  wvec[tid-389] = tanhf(xiS[tid]);
            else if (tid < 457)  fgte[tid-453] = sigm(xiS[tid]);
            else if (tid == 457) sc[1] = sigm(xiS[457]);
            else if (tid == 458) sc[2] = sigm(xiS[458]);
            else if (tid < 463) {
                int r = tid - 459;
                float a0=xiS[459+3*r], a1=xiS[460+3*r], a2=xiS[461+3*r];
                float mx = fmaxf(a0, fmaxf(a1, a2));
                float e0=expf(a0-mx), e1=expf(a1-mx), e2=expf(a2-mx);
                float si = 1.0f/(e0+e1+e2);
                modes[3*r]=e0*si; modes[3*r+1]=e1*si; modes[3*r+2]=e2*si;
            }
            __syncthreads();

            // E2a: old mem norms + key norms
            if (tid < NM) {
                float ssum = 0.0f;
                for (int w = 0; w < NW; ++w) { float v = mem[tid*MS+w]; ssum += v*v; }
                nmo[tid] = sqrtf(ssum);
            } else if (tid < NM+NR) {
                int r = tid - NM; float ssum = 0.0f;
                for (int w = 0; w < NW; ++w) { float v = keys[r*NW+w]; ssum += v*v; }
                nkey[r] = sqrtf(ssum);
            } else if (tid == NM+NR) {
                float ssum = 0.0f;
                for (int w = 0; w < NW; ++w) { float v = wkey[w]; ssum += v*v; }
                sc[3] = sqrtf(ssum);
            }
            __syncthreads();

            // E2b: usage update
            if (tid < NM) {
                float u = usg[tid];
                u = u + (1.0f - u)*wwO[tid];
                float psi = 1.0f;
                #pragma unroll
                for (int r = 0; r < NR; ++r) psi *= (1.0f - fgte[r]*rwS[r*NM+tid]);
                usg[tid] = u*psi;
            }
            __syncthreads();

            // F1: write-content logits
            if (tid < NM) {
                float d = 0.0f;
                for (int w = 0; w < NW; ++w) d += wkey[w]*mem[tid*MS+w];
                wcw[tid] = d/(sc[3]*nmo[tid] + EPSF) * sc[0];
            }
            __syncthreads();
            // F2: softmax over 128
            if (tid < 64) {
                float v = fmaxf(wcw[tid], wcw[tid+64]);
                #pragma unroll
                for (int o = 32; o > 0; o >>= 1) v = fmaxf(v, __shfl_down(v, o));
                if (tid == 0) red[0] = v;
            }
            __syncthreads();
            if (tid < NM) wcw[tid] = expf(wcw[tid] - red[0]);
            __syncthreads();
            if (tid < 64) {
                float v = wave_red(wcw[tid] + wcw[tid+64]);
                if (tid == 0) red[0] = 1.0f/v;
            }
            __syncthreads();
            if (tid < NM) wcw[tid] *= red[0];
            __syncthreads();

            // G1: u
            if (tid < NM) uu[tid] = 5e-6f + (1.0f - 5e-6f)*usg[tid];
            __syncthreads();
            // G2: stable rank
            if (tid < NM) {
                float um = uu[tid]; int rk = 0;
                for (int j = 0; j < NM; ++j) {
                    float uj = uu[j];
                    rk += (uj < um) || (uj == um && j < tid);
                }
                rnk[tid] = rk;
                su[rk] = um;
            }
            __syncthreads();
            // G3: product scan (wave 0)
            if (tid < 64) {
                float a = su[tid], bb = su[64+tid];
                #pragma unroll
                for (int o = 1; o < 64; o <<= 1) {
                    float ta = __shfl_up(a, o);
                    float tb = __shfl_up(bb, o);
                    if (tid >= o) { a *= ta; bb *= tb; }
                }
                float P0 = __shfl(a, 63);
                cum[tid] = a;
                cum[64+tid] = P0*bb;
            }
            __syncthreads();
            // G4: alloc + write weighting
            if (tid < NM) {
                int rk = rnk[tid];
                float excl = (rk == 0) ? 1.0f : cum[rk-1];
                float al = (1.0f - uu[tid])*excl;
                wwN[tid] = sc[2]*(sc[1]*al + (1.0f - sc[1])*wcw[tid]);
            }
            __syncthreads();
            // G5: sum(wwN)
            if (tid < 64) {
                float v = wave_red(wwN[tid] + wwN[tid+64]);
                if (tid == 0) sc[4] = v;
            }
            __syncthreads();

            // H1: mem erase/write + FULL link in-place update
            for (int e = tid; e < NM*NW; e += TPB) {
                int m = e >> 6, w = e & 63;
                float wm = wwN[m];
                mem[m*MS+w] = mem[m*MS+w]*(1.0f - wm*ers[w]) + wm*wvec[w];
            }
            for (int e = tid; e < NM*NM; e += TPB) {
                int i = e >> 7, j = e & 127;
                float nl = (i == j) ? 0.0f
                         : (1.0f - wwN[i] - wwN[j])*lk[e] + wwN[i]*prc[j];
                lk[e] = nl;
            }
            __syncthreads();
            // H2: new mem norms
            if (tid < NM) {
                float ssum = 0.0f;
                for (int w = 0; w < NW; ++w) { float v = mem[tid*MS+w]; ssum += v*v; }
                nmn[tid] = sqrtf(ssum);
            }
            __syncthreads();
            // H3: precedence
            if (tid < NM) prc[tid] = (1.0f - sc[4])*prc[tid] + wwN[tid];
            __syncthreads();

            // I: read-content logits + per-r softmax
            if (tid < NR*NM) {
                int r = tid >> 7, m = tid & 127;
                float d = 0.0f;
                for (int w = 0; w < NW; ++w) d += keys[r*NW+w]*mem[m*MS+w];
                ccw[tid] = d/(nkey[r]*nmn[m] + EPSF) * rstr[r];
            }
            __syncthreads();
            if (tid < 256) {
                int r = tid >> 6, ll = tid & 63;
                float v = fmaxf(ccw[r*NM+ll], ccw[r*NM+ll+64]);
                #pragma unroll
                for (int o = 32; o > 0; o >>= 1) v = fmaxf(v, __shfl_down(v, o));
                if (ll == 0) red[r] = v;
            }
            __syncthreads();
            if (tid < NR*NM) ccw[tid] = expf(ccw[tid] - red[tid>>7]);
            __syncthreads();
            if (tid < 256) {
                int r = tid >> 6, ll = tid & 63;
                float v = wave_red(ccw[r*NM+ll] + ccw[r*NM+ll+64]);
                if (ll == 0) red[4+r] = 1.0f/v;
            }
            __syncthreads();
            if (tid < NR*NM) ccw[tid] *= red[4+(tid>>7)];
            __syncthreads();

            // J1: fwd[r][m] over full link
            {
                const int p0 = wv*32;
                for (int i = 0; i < 32; ++i) {
                    const int p = p0 + i, r = p >> 7, m = p & 127;
                    float partial = lk[m*NM + l]*rwS[r*NM + l]
                                  + lk[m*NM + 64 + l]*rwS[r*NM + 64 + l];
                    partial = wave_red(partial);
                    if (l == 0) fwdT[p] = partial;
                }
            }
            __syncthreads();
            // J2: bwd + mode mix
            float rwnew = 0.0f;
            if (tid < NR*NM) {
                int r = tid >> 7, m = tid & 127;
                float bw = 0.0f;
                for (int i = 0; i < NM; ++i) bw += lk[i*NM+m]*rwS[r*NM+i];
                rwnew = modes[3*r]*bw + modes[3*r+1]*fwdT[tid] + modes[3*r+2]*ccw[tid];
            }
            __syncthreads();
            if (tid < NR*NM) rwS[tid] = rwnew;
            __syncthreads();

            // K: read vectors + publish rv
            if (tid < NR*NW) {
                int r = tid >> 6, w = tid & 63;
                float ssum = 0.0f;
                for (int m = 0; m < NM; ++m) ssum += rwS[r*NM+m]*mem[m*MS+w];
                rv[tid] = ssum;
                cstore(&pubRV[(size_t)par*NBATCH*NR*NW + b*NR*NW + tid], ssum);
            }
            fbump(&flags[F_S2], tid);

            if (tid < NM) wwO[tid] = wwN[tid];
            __syncthreads();
        }
    } else if (bid < 32 + 128) {
        // ========================= GATES block (16 rows) ====================
        const int g = bid - 32;
        const int r = g*16 + wv;
        const float4* WA = (const float4*)(W_ih + (size_t)r*NI);
        float4 wa0 = WA[l], wa1 = WA[l+64], wa2 = WA[l+128];
        const float4* WB = (const float4*)(W_hh + (size_t)r*NH);
        float4 wb0 = WB[l], wb1 = WB[l+64];
        const float bias = b_ih[r] + b_hh[r];

        for (int t = 0; t < NT; ++t) {
            const int par = t & 1, parp = (t+1) & 1;  // read h_{t-1}: parity (t-1)&1
            fwait(&flags[F_S], 32u*(unsigned)(t+1), tid);
            fwait(&flags[F_S2], 32u*(unsigned)(t+1), tid);
            float* gOut = pubG + (size_t)par*NBATCH*NG;
            const float* hIn = pubH + (size_t)parp*NBATCH*NH;
            const float* rIn = pubRV + (size_t)parp*NBATCH*NR*NW;
            for (int p = 0; p < 4; ++p) {
                const int b0 = p*8;
                #pragma unroll
                for (int it = 0; it < 4; ++it) { int idx = tid + it*1024;
                    int bi = idx >> 9, k = idx & 511;
                    S[bi*1280 + k] = x[((size_t)(b0+bi)*NT + t)*NH + k]; }
                #pragma unroll
                for (int it = 0; it < 2; ++it) { int idx = tid + it*1024;
                    int bi = idx >> 8, k = idx & 255;
                    S[bi*1280 + 512 + k] = cload(&rIn[(b0+bi)*NR*NW + k]); }
                #pragma unroll
                for (int it = 0; it < 4; ++it) { int idx = tid + it*1024;
                    int bi = idx >> 9, k = idx & 511;
                    S[bi*1280 + 768 + k] = cload(&hIn[(b0+bi)*NH + k]); }
                __syncthreads();
                #pragma unroll
                for (int bi = 0; bi < 8; ++bi) {
                    const float4* B4 = (const float4*)(S + bi*1280);
                    float acc = dot4(wa0,B4[l]) + dot4(wa1,B4[l+64]) + dot4(wa2,B4[l+128])
                              + dot4(wb0,B4[192+l]) + dot4(wb1,B4[256+l]);
                    acc = wave_red(acc);
                    if (l == 0) cstore(&gOut[(size_t)(b0+bi)*NG + r], acc + bias);
                }
                __syncthreads();
            }
            fbump(&flags[F_G], tid);
        }
    } else if (bid < 32 + 128 + 32) {
        // ========================= XI block (15 rows) =======================
        const int xg = bid - 160;
        const int row = xg*15 + wv;
        const bool act = (wv < 15) && (row < NXI);
        float4 xa0 = {0,0,0,0}, xa1 = {0,0,0,0}; float bias = 0.0f;
        if (act) {
            const float4* WX = (const float4*)(W_xi + (size_t)row*NH);
            xa0 = WX[l]; xa1 = WX[l+64]; bias = b_xi[row];
        }
        for (int t = 0; t < NT; ++t) {
            const int par = t & 1;
            fwait(&flags[F_S], 32u*(unsigned)(t+2), tid);   // h_t ready
            const float* hIn = pubH + (size_t)par*NBATCH*NH;
            float* xOut = pubXI + (size_t)par*NBATCH*480;
            for (int p = 0; p < 4; ++p) {
                const int b0 = p*8;
                #pragma unroll
                for (int it = 0; it < 4; ++it) { int idx = tid + it*1024;
                    int bi = idx >> 9, k = idx & 511;
                    S[bi*512 + k] = cload(&hIn[(b0+bi)*NH + k]); }
                __syncthreads();
                if (act) {
                    #pragma unroll
                    for (int bi = 0; bi < 8; ++bi) {
                        const float4* B4 = (const float4*)(S + bi*512);
                        float acc = dot4(xa0,B4[l]) + dot4(xa1,B4[l+64]);
                        acc = wave_red(acc);
                        if (l == 0) cstore(&xOut[(size_t)(b0+bi)*480 + row], acc + bias);
                    }
                }
                __syncthreads();
            }
            fbump(&flags[F_X], tid);
        }
    } else {
        // ========================= OUT block (8 rows) =======================
        const int og = bid - 192;
        const int row = og*8 + wv;
        const bool act = (wv < 8);
        float4 o0 = {0,0,0,0}, o1 = {0,0,0,0}, o2 = {0,0,0,0}; float bias = 0.0f;
        if (act) {
            const float4* WO = (const float4*)(W_o + (size_t)row*NI);
            o0 = WO[l]; o1 = WO[l+64]; o2 = WO[l+128]; bias = b_o[row];
        }
        for (int t = 0; t < NT; ++t) {
            const int par = t & 1;
            fwait(&flags[F_S], 32u*(unsigned)(t+2), tid);   // h_t
            fwait(&flags[F_S2], 32u*(unsigned)(t+2), tid);  // rv_t
            const float* hIn = pubH + (size_t)par*NBATCH*NH;
            const float* rIn = pubRV + (size_t)par*NBATCH*NR*NW;
            for (int p = 0; p < 4; ++p) {
                const int b0 = p*8;
                #pragma unroll
                for (int it = 0; it < 4; ++it) { int idx = tid + it*1024;
                    int bi = idx >> 9, k = idx & 511;
                    S[bi*768 + k] = cload(&hIn[(b0+bi)*NH + k]); }
                #pragma unroll
                for (int it = 0; it < 2; ++it) { int idx = tid + it*1024;
                    int bi = idx >> 8, k = idx & 255;
                    S[bi*768 + 512 + k] = cload(&rIn[(b0+bi)*NR*NW + k]); }
                __syncthreads();
                if (act) {
                    #pragma unroll
                    for (int bi = 0; bi < 8; ++bi) {
                        const float4* B4 = (const float4*)(S + bi*768);
                        float acc = dot4(o0,B4[l]) + dot4(o1,B4[l+64]) + dot4(o2,B4[128+l]);
                        acc = wave_red(acc);
                        if (l == 0) out[((size_t)(b0+bi)*NT + t)*NH + row] = acc + bias;
                    }
                }
                __syncthreads();
            }
            fbump(&flags[F_O], tid);
        }
    }
}

extern "C" void kernel_launch(void* const* d_in, const int* in_sizes, int n_in,
                              void* d_out, int out_size, void* d_ws, size_t ws_size,
                              hipStream_t stream) {
    (void)in_sizes; (void)n_in; (void)out_size; (void)ws_size;
    const float* x    = (const float*)d_in[0];
    const float* W_ih = (const float*)d_in[1];
    const float* W_hh = (const float*)d_in[2];
    const float* b_ih = (const float*)d_in[3];
    const float* b_hh = (const float*)d_in[4];
    const float* W_xi = (const float*)d_in[5];
    const float* b_xi = (const float*)d_in[6];
    const float* W_o  = (const float*)d_in[7];
    const float* b_o  = (const float*)d_in[8];
    float* out = (float*)d_out;
    float* ws  = (float*)d_ws;

    dnc_zero<<<1, 256, 0, stream>>>(ws);

    void* args[] = { (void*)&x, (void*)&W_ih, (void*)&W_hh, (void*)&b_ih,
                     (void*)&b_hh, (void*)&W_xi, (void*)&b_xi, (void*)&W_o,
                     (void*)&b_o, (void*)&out, (void*)&ws };
    hipLaunchCooperativeKernel((void*)dnc_gemm, dim3(NBLK), dim3(TPB),
                               args, 0, stream);
}